// Round 20
// baseline (65.635 us; speedup 1.0000x reference)
//
#include <hip/hip_runtime.h>

#define HID 64
#define NTOK 66          // VOCAB_SIZE + 2
#define SEQ 64
#define WIN0 55          // SEQ_LEN - 1 - MEMORY_SLOTS
#define NW 8
#define LDS_STRIDE 72    // ushorts per table row (144B)
#define ITERS 16         // iterations per block (rows/block = 2048, grid = 256)
#define BLOCK 512        // 8 waves
#define ROWS_PER_ITER 128 // 8 waves x 16 rows

typedef _Float16 half8 __attribute__((ext_vector_type(8)));
typedef unsigned short ushort8v __attribute__((ext_vector_type(8)));
typedef float float4v __attribute__((ext_vector_type(4)));

static __device__ __forceinline__ unsigned short f2h(float f) {
    _Float16 h = (_Float16)f;
    union { _Float16 h; unsigned short u; } v; v.h = h;
    return v.u;
}

// Kernel 1: tables T1[t][n] = b1[n] + sum_k emb[t][k]*W1[n][k]
//           T2[t][n] = 0.125 * sum_k emb[t][k]*W1[n][64+k]   (f16)
__global__ void build_tables(const float* __restrict__ embed,
                             const float* __restrict__ W1,
                             const float* __restrict__ b1,
                             unsigned short* __restrict__ tbl) {
    int b = blockIdx.x;      // 0..131
    int tb = b & 1;
    int t  = b >> 1;
    int n  = threadIdx.x;    // 0..63
    float acc = tb ? 0.0f : b1[n];
    const float* er = embed + t * HID;
    const float* wr = W1 + n * (2 * HID) + tb * HID;
#pragma unroll 8
    for (int k = 0; k < HID; ++k) acc += er[k] * wr[k];
    if (tb) acc *= 0.125f;
    tbl[tb * (NTOK * HID) + t * HID + n] = f2h(acc);
}

// Kernel 2: logits^T = W2 (A-op) x h^T (B-op) via mfma_f32_16x16x32_f16.
// SPLIT-PIPE GATHER: per chunk, 4 T2 rows from LDS (rotating reissue) and
// T1 + 4 T2 rows from GLOBAL through L1 (17KB table is L1-resident; lines
// re-touched every ~7 wave-iters stay MRU-hot against streaming evictions).
// Global gathers are reissued AFTER consume and BEFORE the iteration's
// stores, so in-order vmcnt retirement never queues them behind store
// drain. Moves ~55% of the LDS-pipe time onto the near-idle VMEM pipe.
// R19 skeleton: grid=256 (1 block/CU, prologue paid once), depth-2 token
// prefetch, bias in MFMA C-operand.
// Falsified levers (do not revisit): nontemporal hints (R10 -43%), 545KB
// pair-table global gather (R13, L2-evicted by store stream), s_sleep
// stagger (R14 null), zero-load loop (R17 -3.2), cooperative bank-uniform
// gather (R18: conflict counter is intrinsic b128 multi-pass + balls-in-
// bins, irreducible), more waves (R5-R8,R15: residency HW-capped ~2/SIMD).
__global__ __launch_bounds__(BLOCK, 2) void fused_forward(
    const int* __restrict__ seqs,
    const int* __restrict__ qtok,
    const float* __restrict__ W2,
    const float* __restrict__ b2,
    const unsigned short* __restrict__ tbl,
    float* __restrict__ out)
{
    __shared__ unsigned short T_lds[2 * NTOK * LDS_STRIDE]; // 19008 B

    int tid  = threadIdx.x;
    int wv   = tid >> 6;        // 0..7
    int l    = tid & 63;
    int lrow = l & 15;          // W2 row within n-tile / batch row within tile
    int lg   = l >> 4;
    int lk8  = lg * 8;          // k offset within 32-wide K chunk (ushorts)

    int row0 = blockIdx.x * (ITERS * ROWS_PER_ITER) + wv * 16 + lrow;

    const unsigned short* t1g = tbl;                 // T1 global (L1-hot)
    const unsigned short* t2g = tbl + NTOK * HID;    // T2 global (L1-hot)

    int qA, qB;
    int wA[NW], wB[NW];
    half8  gl0[4], gl1[4];      // LDS-sourced T2 rows j=0..3, chunks 0/1
    half8  gg0[5], gg1[5];      // global-sourced [T1, T2 j=4..7], chunks 0/1
    half8  a0, a1;
    float4v acc4[4];

// scalar token loads (proven-clean HBM traffic)
#define LOADT(s, t_) { \
    int row_ = row0 + (t_) * ROWS_PER_ITER; \
    q##s = qtok[row_]; \
    const int* sp_ = seqs + row_ * SEQ + WIN0; \
    _Pragma("unroll") \
    for (int j = 0; j < NW; ++j) w##s[j] = sp_[j]; \
}

// prologue fill of one chunk's stage (after barrier; LDS table ready)
#define GATHER_ALL(gl, gg, qq, ww, k0c) { \
    (gg)[0] = *(const half8*)(t1g + (qq) * HID + (k0c)); \
    _Pragma("unroll") \
    for (int j = 0; j < 4; ++j) { \
        (gl)[j] = *(const half8*)(T_lds + NTOK * LDS_STRIDE + (ww)[j] * LDS_STRIDE + (k0c)); \
        (gg)[j + 1] = *(const half8*)(t2g + (ww)[j + 4] * HID + (k0c)); \
    } \
}

// consume stage (sum+relu) while REISSUING both LDS and global slots with
// NEXT ITER's tokens. Global loads are issued here -- before this
// iteration's stores -- so vmcnt retirement never waits on store drain.
#define SUMG_REISSUE(aout, gl, gg, qq, ww, k0c) { \
    half8 s_ = (gg)[0]; \
    (gg)[0] = *(const half8*)(t1g + (qq) * HID + (k0c)); \
    _Pragma("unroll") \
    for (int j = 0; j < 4; ++j) { \
        s_ += (gl)[j]; \
        (gl)[j] = *(const half8*)(T_lds + NTOK * LDS_STRIDE + (ww)[j] * LDS_STRIDE + (k0c)); \
    } \
    _Pragma("unroll") \
    for (int j = 0; j < 4; ++j) { \
        s_ += (gg)[j + 1]; \
        (gg)[j + 1] = *(const half8*)(t2g + (ww)[j + 4] * HID + (k0c)); \
    } \
    half8 z_ = (half8)(_Float16)0; \
    aout = __builtin_elementwise_max(s_, z_); \
}

// final consume, no reissue
#define SUM_FINAL(aout, gl, gg) { \
    half8 s_ = (gg)[0]; \
    _Pragma("unroll") \
    for (int j = 0; j < 4; ++j) { s_ += (gl)[j]; s_ += (gg)[j + 1]; } \
    half8 z_ = (half8)(_Float16)0; \
    aout = __builtin_elementwise_max(s_, z_); \
}

// first K-half of the MFMAs (C init = bias)
#define MFMA_K0 { \
    _Pragma("unroll") \
    for (int nt = 0; nt < 4; ++nt) \
        acc4[nt] = __builtin_amdgcn_mfma_f32_16x16x32_f16(wfrag[nt][0], a0, b2v[nt], 0, 0, 0); \
}

// second K-half + stores (after ALL this iter's gather loads are issued)
#define MFMA_K1_ST(t_) { \
    float* op = out + (size_t)(row0 + (t_) * ROWS_PER_ITER) * HID; \
    _Pragma("unroll") \
    for (int nt = 0; nt < 4; ++nt) { \
        acc4[nt] = __builtin_amdgcn_mfma_f32_16x16x32_f16(wfrag[nt][1], a1, acc4[nt], 0, 0, 0); \
        *(float4v*)(op + nt * 16 + lg * 4) = acc4[nt]; \
    } \
}

// iter t: consume stages (pre-filled with t's tokens), reissue with t+1's
// (N) tokens; prefetch tokens for t+2 into C's (now dead) slots.
#define ITER_MID(C, N, t_) { \
    SUMG_REISSUE(a0, gl0, gg0, q##N, w##N, lk8); \
    MFMA_K0; \
    SUMG_REISSUE(a1, gl1, gg1, q##N, w##N, 32 + lk8); \
    MFMA_K1_ST(t_); \
    LOADT(C, (t_) + 2); \
}
#define ITER_NOLOAD(C, N, t_) { \
    SUMG_REISSUE(a0, gl0, gg0, q##N, w##N, lk8); \
    MFMA_K0; \
    SUMG_REISSUE(a1, gl1, gg1, q##N, w##N, 32 + lk8); \
    MFMA_K1_ST(t_); \
}
#define ITER_LAST(t_) { \
    SUM_FINAL(a0, gl0, gg0); \
    MFMA_K0; \
    SUM_FINAL(a1, gl1, gg1); \
    MFMA_K1_ST(t_); \
}

    // ---- (1) iter 0/1 token loads: HBM latency hides under W2+fill+barrier ----
    LOADT(A, 0);
    LOADT(B, 1);

    // ---- (2) W2 A-fragments in registers (whole 64x64, f16) + b2 float4 ----
    half8   wfrag[4][2];
    float4v b2v[4];
#pragma unroll
    for (int nt = 0; nt < 4; ++nt) {
        b2v[nt] = *(const float4v*)(b2 + nt * 16 + lg * 4);
#pragma unroll
        for (int kc = 0; kc < 2; ++kc) {
            const float* wp = W2 + (nt * 16 + lrow) * HID + kc * 32 + lk8;
            half8 f;
#pragma unroll
            for (int j = 0; j < 8; ++j) f[j] = (_Float16)wp[j];
            wfrag[nt][kc] = f;
        }
    }

    // ---- (3) fill LDS tables (16B chunks; row stride 144B) ----
    for (int i = tid; i < 2 * NTOK * (HID / 8); i += BLOCK) {
        int tbi = i / (NTOK * 8);
        int rem = i - tbi * (NTOK * 8);
        int t   = rem >> 3;
        int kq  = (rem & 7) << 3;
        *(ushort8v*)(T_lds + tbi * (NTOK * LDS_STRIDE) + t * LDS_STRIDE + kq) =
            *(const ushort8v*)(tbl + tbi * (NTOK * HID) + t * HID + kq);
    }
    __syncthreads();

    // ---- (4) split-pipe depth-2 pipeline over 16 iterations (all static) ----
    GATHER_ALL(gl0, gg0, qA, wA, lk8);        // iter0 chunk0
    GATHER_ALL(gl1, gg1, qA, wA, 32 + lk8);   // iter0 chunk1

    ITER_MID(A, B, 0);
    ITER_MID(B, A, 1);
    ITER_MID(A, B, 2);
    ITER_MID(B, A, 3);
    ITER_MID(A, B, 4);
    ITER_MID(B, A, 5);
    ITER_MID(A, B, 6);
    ITER_MID(B, A, 7);
    ITER_MID(A, B, 8);
    ITER_MID(B, A, 9);
    ITER_MID(A, B, 10);
    ITER_MID(B, A, 11);
    ITER_MID(A, B, 12);
    ITER_MID(B, A, 13);
    ITER_NOLOAD(A, B, 14);  // consume A(14), reissue B(15)
    ITER_LAST(15);          // consume B(15)

#undef LOADT
#undef GATHER_ALL
#undef SUMG_REISSUE
#undef SUM_FINAL
#undef MFMA_K0
#undef MFMA_K1_ST
#undef ITER_MID
#undef ITER_NOLOAD
#undef ITER_LAST
}

extern "C" void kernel_launch(void* const* d_in, const int* in_sizes, int n_in,
                              void* d_out, int out_size, void* d_ws, size_t ws_size,
                              hipStream_t stream) {
    const int*   seqs  = (const int*)d_in[0];
    const int*   qtok  = (const int*)d_in[1];
    const float* embed = (const float*)d_in[2];
    const float* W1    = (const float*)d_in[3];
    const float* b1    = (const float*)d_in[4];
    const float* W2    = (const float*)d_in[5];
    const float* b2    = (const float*)d_in[6];
    float* out = (float*)d_out;
    unsigned short* tbl = (unsigned short*)d_ws;

    int B = in_sizes[0] / SEQ;

    build_tables<<<NTOK * 2, HID, 0, stream>>>(embed, W1, b1, tbl);

    int grid = B / (ITERS * ROWS_PER_ITER);
    fused_forward<<<grid, BLOCK, 0, stream>>>(seqs, qtok, W2, b2, tbl, out);
}

// Round 21
// 44.798 us; speedup vs baseline: 1.4651x; 1.4651x over previous
//
#include <hip/hip_runtime.h>

#define HID 64
#define NTOK 66           // VOCAB_SIZE + 2
#define SEQ 64
#define WIN0 55           // SEQ_LEN - 1 - MEMORY_SLOTS
#define NW 8
#define LDS_STRIDE 72     // ushorts per table/h row (144B)
#define ITERS 16          // iterations per block (rows/block = 2048, grid = 256)
#define BLOCK 512         // 8 waves: 0-3 producers, 4-7 consumers
#define ROWS_PER_ITER 128 // 8 tiles x 16 rows
#define HOFF (2 * NTOK * LDS_STRIDE)       // ushort offset of h region
#define HBUF (ROWS_PER_ITER * LDS_STRIDE)  // one h buffer (ushorts)

typedef _Float16 half8 __attribute__((ext_vector_type(8)));
typedef unsigned short ushort8v __attribute__((ext_vector_type(8)));
typedef float float4v __attribute__((ext_vector_type(4)));

static __device__ __forceinline__ unsigned short f2h(float f) {
    _Float16 h = (_Float16)f;
    union { _Float16 h; unsigned short u; } v; v.h = h;
    return v.u;
}

// Kernel 1: tables T1[t][n] = b1[n] + sum_k emb[t][k]*W1[n][k]
//           T2[t][n] = 0.125 * sum_k emb[t][k]*W1[n][64+k]   (f16)
__global__ void build_tables(const float* __restrict__ embed,
                             const float* __restrict__ W1,
                             const float* __restrict__ b1,
                             unsigned short* __restrict__ tbl) {
    int b = blockIdx.x;      // 0..131
    int tb = b & 1;
    int t  = b >> 1;
    int n  = threadIdx.x;    // 0..63
    float acc = tb ? 0.0f : b1[n];
    const float* er = embed + t * HID;
    const float* wr = W1 + n * (2 * HID) + tb * HID;
#pragma unroll 8
    for (int k = 0; k < HID; ++k) acc += er[k] * wr[k];
    if (tb) acc *= 0.125f;
    tbl[tb * (NTOK * HID) + t * HID + n] = f2h(acc);
}

// Kernel 2: PRODUCER/CONSUMER WAVE SPECIALIZATION.
// Waves 0-3 (producers): token loads + LDS table gather + f16 sum/relu ->
//   write h rows to double-buffered LDS. They issue NO stores.
// Waves 4-7 (consumers): read h fragments -> MFMA (bias in C) -> store.
//   They issue NO gathers; VMEM carries only the store stream.
// One __syncthreads per iteration: consumers drain buf[t&1] while
// producers fill buf[(t+1)&1] -> LDS/VALU pipe and HBM store pipe run
// CONCURRENTLY by construction instead of phase-alternating in lockstep
// (R12-R20 evidence: wall == sum of pipe times; all within-wave fixes
// null or negative). Wave w handles tiles (w&3) and (w&3)+4 of each
// 128-row iteration, so producer->consumer tile mapping is 1:1.
__global__ __launch_bounds__(BLOCK, 2) void fused_forward(
    const int* __restrict__ seqs,
    const int* __restrict__ qtok,
    const float* __restrict__ W2,
    const float* __restrict__ b2,
    const unsigned short* __restrict__ tbl,
    float* __restrict__ out)
{
    // tables 19008 B + 2 h-buffers (128 rows x 144 B) 36864 B = 55872 B
    __shared__ unsigned short T_lds[HOFF + 2 * HBUF];

    int tid  = threadIdx.x;
    int wv   = tid >> 6;        // 0..7
    int l    = tid & 63;
    int lrow = l & 15;          // row within tile / W2 row within n-tile
    int lg   = l >> 4;          // k-chunk quarter / output col group
    int lk8  = lg * 8;          // k offset within 32-wide K chunk (ushorts)
    int tile0 = wv & 3;         // this wave's tiles: tile0 and tile0+4

    int blk0 = blockIdx.x * (ITERS * ROWS_PER_ITER);
    // producer token rows for its 2 tiles (iter t adds t*128)
    int prow0 = blk0 + tile0 * 16 + lrow;
    int prow1 = prow0 + 64;

    int qA0, qA1, qB0, qB1;
    int wA0[NW], wA1[NW], wB0[NW], wB1[NW];

// producer token loads for iter t_ (guard folds at compile time)
#define LOADT(S, t_) if ((t_) < ITERS) { \
    int r0_ = prow0 + (t_) * ROWS_PER_ITER; \
    int r1_ = prow1 + (t_) * ROWS_PER_ITER; \
    q##S##0 = qtok[r0_]; \
    q##S##1 = qtok[r1_]; \
    const int* s0_ = seqs + r0_ * SEQ + WIN0; \
    const int* s1_ = seqs + r1_ * SEQ + WIN0; \
    _Pragma("unroll") \
    for (int j = 0; j < NW; ++j) { w##S##0[j] = s0_[j]; w##S##1[j] = s1_[j]; } \
}

#define RD_T1(qq, koff) (*(const half8*)(T_lds + (qq) * LDS_STRIDE + (koff)))
#define RD_T2(ww, koff) (*(const half8*)(T_lds + NTOK * LDS_STRIDE + (ww) * LDS_STRIDE + (koff)))

// producer: gather+sum+relu both tiles, write 4 half8 rows to buf_
#define PRODUCE(S, buf_) { \
    unsigned short* hb_ = T_lds + HOFF + (buf_) * HBUF; \
    half8 s0_ = RD_T1(q##S##0, lk8); \
    half8 s1_ = RD_T1(q##S##0, 32 + lk8); \
    half8 u0_ = RD_T1(q##S##1, lk8); \
    half8 u1_ = RD_T1(q##S##1, 32 + lk8); \
    _Pragma("unroll") \
    for (int j = 0; j < NW; ++j) { \
        s0_ += RD_T2(w##S##0[j], lk8); \
        s1_ += RD_T2(w##S##0[j], 32 + lk8); \
        u0_ += RD_T2(w##S##1[j], lk8); \
        u1_ += RD_T2(w##S##1[j], 32 + lk8); \
    } \
    half8 z_ = (half8)(_Float16)0; \
    s0_ = __builtin_elementwise_max(s0_, z_); \
    s1_ = __builtin_elementwise_max(s1_, z_); \
    u0_ = __builtin_elementwise_max(u0_, z_); \
    u1_ = __builtin_elementwise_max(u1_, z_); \
    unsigned short* r0_ = hb_ + (tile0 * 16 + lrow) * LDS_STRIDE; \
    unsigned short* r1_ = hb_ + ((tile0 + 4) * 16 + lrow) * LDS_STRIDE; \
    *(half8*)(r0_ + lk8) = s0_; \
    *(half8*)(r0_ + 32 + lk8) = s1_; \
    *(half8*)(r1_ + lk8) = u0_; \
    *(half8*)(r1_ + 32 + lk8) = u1_; \
}

// consumer: read h fragments for both tiles, MFMA, store
#define CONSUME(t_, buf_) { \
    const unsigned short* hb_ = T_lds + HOFF + (buf_) * HBUF; \
    _Pragma("unroll") \
    for (int pt = 0; pt < 2; ++pt) { \
        int trow_ = (tile0 + pt * 4) * 16 + lrow; \
        half8 a0_ = *(const half8*)(hb_ + trow_ * LDS_STRIDE + lk8); \
        half8 a1_ = *(const half8*)(hb_ + trow_ * LDS_STRIDE + 32 + lk8); \
        float* op_ = out + (size_t)(blk0 + (t_) * ROWS_PER_ITER + trow_) * HID; \
        _Pragma("unroll") \
        for (int nt = 0; nt < 4; ++nt) { \
            float4v acc_ = __builtin_amdgcn_mfma_f32_16x16x32_f16(wfrag[nt][0], a0_, b2v[nt], 0, 0, 0); \
            acc_ = __builtin_amdgcn_mfma_f32_16x16x32_f16(wfrag[nt][1], a1_, acc_, 0, 0, 0); \
            *(float4v*)(op_ + nt * 16 + lg * 4) = acc_; \
        } \
    } \
}

// one iteration: consumers drain buf[t&1]; producers fill buf[(t+1)&1].
// ITER_E for even t (produce uses stage B), ITER_O for odd t (stage A).
#define ITER_E(t_) { \
    if (wv >= 4) { CONSUME(t_, (t_) & 1); } \
    else if ((t_) + 1 < ITERS) { PRODUCE(B, ((t_) + 1) & 1); LOADT(B, (t_) + 3); } \
    __syncthreads(); \
}
#define ITER_O(t_) { \
    if (wv >= 4) { CONSUME(t_, (t_) & 1); } \
    else if ((t_) + 1 < ITERS) { PRODUCE(A, ((t_) + 1) & 1); LOADT(A, (t_) + 3); } \
    __syncthreads(); \
}

    // ---- (1) producers: iter 0/1 tokens (latency under fill+barrier) ----
    half8   wfrag[4][2];
    float4v b2v[4];
    if (wv < 4) {
        LOADT(A, 0);
        LOADT(B, 1);
    } else {
        // ---- (2) consumers: W2 A-fragments (whole 64x64, f16) + b2 ----
#pragma unroll
        for (int nt = 0; nt < 4; ++nt) {
            b2v[nt] = *(const float4v*)(b2 + nt * 16 + lg * 4);
#pragma unroll
            for (int kc = 0; kc < 2; ++kc) {
                const float* wp = W2 + (nt * 16 + lrow) * HID + kc * 32 + lk8;
                half8 f;
#pragma unroll
                for (int j = 0; j < 8; ++j) f[j] = (_Float16)wp[j];
                wfrag[nt][kc] = f;
            }
        }
    }

    // ---- (3) all waves: fill LDS tables (16B chunks; row stride 144B) ----
    for (int i = tid; i < 2 * NTOK * (HID / 8); i += BLOCK) {
        int tbi = i / (NTOK * 8);
        int rem = i - tbi * (NTOK * 8);
        int t   = rem >> 3;
        int kq  = (rem & 7) << 3;
        *(ushort8v*)(T_lds + tbi * (NTOK * LDS_STRIDE) + t * LDS_STRIDE + kq) =
            *(const ushort8v*)(tbl + tbi * (NTOK * HID) + t * HID + kq);
    }
    __syncthreads();

    // ---- (4) pipeline prologue: producers fill buf0 with iter 0's h ----
    if (wv < 4) {
        PRODUCE(A, 0);
        LOADT(A, 2);
    }
    __syncthreads();

    // ---- (5) 16 iterations: consume(t) || produce(t+1) ----
    ITER_E(0);  ITER_O(1);  ITER_E(2);  ITER_O(3);
    ITER_E(4);  ITER_O(5);  ITER_E(6);  ITER_O(7);
    ITER_E(8);  ITER_O(9);  ITER_E(10); ITER_O(11);
    ITER_E(12); ITER_O(13); ITER_E(14); ITER_O(15);

#undef LOADT
#undef RD_T1
#undef RD_T2
#undef PRODUCE
#undef CONSUME
#undef ITER_E
#undef ITER_O
}

extern "C" void kernel_launch(void* const* d_in, const int* in_sizes, int n_in,
                              void* d_out, int out_size, void* d_ws, size_t ws_size,
                              hipStream_t stream) {
    const int*   seqs  = (const int*)d_in[0];
    const int*   qtok  = (const int*)d_in[1];
    const float* embed = (const float*)d_in[2];
    const float* W1    = (const float*)d_in[3];
    const float* b1    = (const float*)d_in[4];
    const float* W2    = (const float*)d_in[5];
    const float* b2    = (const float*)d_in[6];
    float* out = (float*)d_out;
    unsigned short* tbl = (unsigned short*)d_ws;

    int B = in_sizes[0] / SEQ;

    build_tables<<<NTOK * 2, HID, 0, stream>>>(embed, W1, b1, tbl);

    int grid = B / (ITERS * ROWS_PER_ITER);
    fused_forward<<<grid, BLOCK, 0, stream>>>(seqs, qtok, W2, b2, tbl, out);
}